// Round 1
// baseline (727.745 us; speedup 1.0000x reference)
//
#include <hip/hip_runtime.h>

typedef __bf16 bf16;
typedef __attribute__((ext_vector_type(8))) bf16 bf16x8;
typedef __attribute__((ext_vector_type(4))) float f32x4;

#define MFMA_BF16(a, b, c) __builtin_amdgcn_mfma_f32_16x16x32_bf16((a), (b), (c), 0, 0, 0)

constexpr int S_LEN = 2048;
constexpr int EMB   = 1024;
constexpr int NHEAD = 16;
constexpr int HDIM  = 64;
constexpr int BATCH = 4;
constexpr int NTOK  = BATCH * S_LEN;   // 8192
constexpr int LDS_STRIDE = 40;         // halfwords/row: 32 + 8 pad -> 80B rows, 16B-aligned, 2-way banks (free)

// ---------------------------------------------------------------------------
// NT GEMM: C[M,N] = A[M,K] * W[N,K]^T + bias.  M=8192, N=K=1024.
// 128x128 block tile, BK=32, 256 threads = 4 waves in 2x2, each wave 64x64.
// AFP32: A is fp32 (cast to bf16 during LDS staging) else bf16.
// MODE 0: C bf16 [M,EMB]; MODE 1: C bf16 scattered to Vt[b,h,d,s]; MODE 2: C fp32.
// ---------------------------------------------------------------------------
template <bool AFP32, int MODE>
__global__ __launch_bounds__(256)
void gemm_nt_kern(const void* __restrict__ Aptr,
                  const float* __restrict__ Wptr,
                  const float* __restrict__ bias,
                  void* __restrict__ Cptr)
{
    __shared__ bf16 alds[128 * LDS_STRIDE];
    __shared__ bf16 blds[128 * LDS_STRIDE];

    const int tid  = threadIdx.x;
    const int lane = tid & 63;
    const int w    = tid >> 6;
    const int quad = lane >> 4;
    const int l16  = lane & 15;
    const int wm   = (w >> 1) * 64;
    const int wn   = (w & 1) * 64;
    const int m0   = blockIdx.x * 128;
    const int n0   = blockIdx.y * 128;

    f32x4 acc[4][4] = {};

    for (int k0 = 0; k0 < EMB; k0 += 32) {
        // ---- stage A tile (128 rows x 32 k) ----
        if constexpr (AFP32) {
            const float* A = (const float*)Aptr;
            #pragma unroll
            for (int c = 0; c < 4; ++c) {
                int idx = tid * 4 + c;          // 0..1023 float4 chunks
                int row = idx >> 3;
                int j   = idx & 7;
                f32x4 v = *(const f32x4*)(A + (size_t)(m0 + row) * EMB + k0 + j * 4);
                bf16* dst = &alds[row * LDS_STRIDE + j * 4];
                dst[0] = (bf16)v[0]; dst[1] = (bf16)v[1];
                dst[2] = (bf16)v[2]; dst[3] = (bf16)v[3];
            }
        } else {
            const bf16* A = (const bf16*)Aptr;
            #pragma unroll
            for (int c = 0; c < 2; ++c) {
                int idx = tid * 2 + c;          // 0..511 16B chunks
                int row = idx >> 2;
                int j   = idx & 3;
                *(bf16x8*)&alds[row * LDS_STRIDE + j * 8] =
                    *(const bf16x8*)(A + (size_t)(m0 + row) * EMB + k0 + j * 8);
            }
        }
        // ---- stage W tile (128 rows x 32 k), fp32 -> bf16 ----
        #pragma unroll
        for (int c = 0; c < 4; ++c) {
            int idx = tid * 4 + c;
            int row = idx >> 3;
            int j   = idx & 7;
            f32x4 v = *(const f32x4*)(Wptr + (size_t)(n0 + row) * EMB + k0 + j * 4);
            bf16* dst = &blds[row * LDS_STRIDE + j * 4];
            dst[0] = (bf16)v[0]; dst[1] = (bf16)v[1];
            dst[2] = (bf16)v[2]; dst[3] = (bf16)v[3];
        }
        __syncthreads();

        bf16x8 afrag[4], bfrag[4];
        #pragma unroll
        for (int t = 0; t < 4; ++t)
            afrag[t] = *(const bf16x8*)&alds[(wm + t * 16 + l16) * LDS_STRIDE + quad * 8];
        #pragma unroll
        for (int t = 0; t < 4; ++t)
            bfrag[t] = *(const bf16x8*)&blds[(wn + t * 16 + l16) * LDS_STRIDE + quad * 8];

        #pragma unroll
        for (int mt = 0; mt < 4; ++mt)
            #pragma unroll
            for (int nt = 0; nt < 4; ++nt)
                acc[mt][nt] = MFMA_BF16(afrag[mt], bfrag[nt], acc[mt][nt]);

        __syncthreads();
    }

    // ---- epilogue: C row = quad*4+reg, col = l16 (m89-verified layout) ----
    #pragma unroll
    for (int mt = 0; mt < 4; ++mt) {
        #pragma unroll
        for (int nt = 0; nt < 4; ++nt) {
            int col = n0 + wn + nt * 16 + l16;
            float bv = bias[col];
            #pragma unroll
            for (int r = 0; r < 4; ++r) {
                int row = m0 + wm + mt * 16 + quad * 4 + r;
                float v = acc[mt][nt][r] + bv;
                if constexpr (MODE == 0) {
                    ((bf16*)Cptr)[(size_t)row * EMB + col] = (bf16)v;
                } else if constexpr (MODE == 1) {
                    int b = row >> 11, s = row & 2047;
                    int h = col >> 6, d = col & 63;
                    ((bf16*)Cptr)[(size_t)((b * NHEAD + h) * HDIM + d) * S_LEN + s] = (bf16)v;
                } else {
                    ((float*)Cptr)[(size_t)row * EMB + col] = v;
                }
            }
        }
    }
}

// ---------------------------------------------------------------------------
// Flash attention. Grid (S/128, H, B), 256 threads = 4 waves.
// Wave w owns query rows [w*32, w*32+32) of the 128-row Q tile.
// Q/K fragments loaded directly from global q/k [8192,1024] bf16 (NT pattern);
// V read from pre-transposed Vt[b,h,d,s]; P routed C-layout -> A-layout via LDS.
// ---------------------------------------------------------------------------
__global__ __launch_bounds__(256)
void flash_attn_kern(const bf16* __restrict__ qg, const bf16* __restrict__ kg,
                     const bf16* __restrict__ vtg, const int* __restrict__ maskg,
                     bf16* __restrict__ ctx)
{
    __shared__ bf16 plds[128 * 136];   // 136 halfword stride: 272B rows, 16B-aligned, 2-way banks

    const int tid  = threadIdx.x;
    const int lane = tid & 63;
    const int w    = tid >> 6;
    const int quad = lane >> 4;
    const int l16  = lane & 15;
    const int b    = blockIdx.z;
    const int h    = blockIdx.y;
    const int q0   = blockIdx.x * 128;
    const float qk_scale = 0.125f * 1.44269504088896340736f;  // 1/sqrt(64) * log2(e)

    // Q fragments held in registers for the whole kernel: 2 row-tiles x 2 k-steps
    bf16x8 qf[2][2];
    #pragma unroll
    for (int mt = 0; mt < 2; ++mt)
        #pragma unroll
        for (int ks = 0; ks < 2; ++ks) {
            int row = b * S_LEN + q0 + w * 32 + mt * 16 + l16;
            qf[mt][ks] = *(const bf16x8*)(qg + (size_t)row * EMB + h * HDIM + ks * 32 + quad * 8);
        }

    float mrow[2][4], lrow[2][4];
    f32x4 oacc[2][4] = {};
    #pragma unroll
    for (int mt = 0; mt < 2; ++mt)
        #pragma unroll
        for (int r = 0; r < 4; ++r) { mrow[mt][r] = -1e30f; lrow[mt][r] = 0.f; }

    for (int kt = 0; kt < 16; ++kt) {
        const int k0 = kt * 128;

        // ---- S = Q K^T over this 128-key tile ----
        f32x4 sacc[2][8] = {};
        #pragma unroll
        for (int nt = 0; nt < 8; ++nt) {
            int krow = b * S_LEN + k0 + nt * 16 + l16;
            #pragma unroll
            for (int ks = 0; ks < 2; ++ks) {
                bf16x8 kf = *(const bf16x8*)(kg + (size_t)krow * EMB + h * HDIM + ks * 32 + quad * 8);
                sacc[0][nt] = MFMA_BF16(qf[0][ks], kf, sacc[0][nt]);
                sacc[1][nt] = MFMA_BF16(qf[1][ks], kf, sacc[1][nt]);
            }
        }

        // ---- scale + mask + row max (sentinels finite: -3e38 masked, -1e30 init) ----
        float rmax[2][4];
        #pragma unroll
        for (int mt = 0; mt < 2; ++mt)
            #pragma unroll
            for (int r = 0; r < 4; ++r) rmax[mt][r] = -3.0e38f;
        #pragma unroll
        for (int nt = 0; nt < 8; ++nt) {
            int mv = maskg[b * S_LEN + k0 + nt * 16 + l16];  // col = l16 for all regs
            #pragma unroll
            for (int mt = 0; mt < 2; ++mt)
                #pragma unroll
                for (int r = 0; r < 4; ++r) {
                    float sv = sacc[mt][nt][r] * qk_scale;
                    sv = mv ? sv : -3.0e38f;
                    sacc[mt][nt][r] = sv;
                    rmax[mt][r] = fmaxf(rmax[mt][r], sv);
                }
        }
        #pragma unroll
        for (int d = 1; d < 16; d <<= 1)
            #pragma unroll
            for (int mt = 0; mt < 2; ++mt)
                #pragma unroll
                for (int r = 0; r < 4; ++r)
                    rmax[mt][r] = fmaxf(rmax[mt][r], __shfl_xor(rmax[mt][r], d));

        // ---- online softmax update ----
        float mnew[2][4], alpha[2][4], rsum[2][4];
        #pragma unroll
        for (int mt = 0; mt < 2; ++mt)
            #pragma unroll
            for (int r = 0; r < 4; ++r) {
                mnew[mt][r]  = fmaxf(mrow[mt][r], rmax[mt][r]);
                alpha[mt][r] = __builtin_amdgcn_exp2f(mrow[mt][r] - mnew[mt][r]);
                rsum[mt][r]  = 0.f;
            }
        #pragma unroll
        for (int nt = 0; nt < 8; ++nt)
            #pragma unroll
            for (int mt = 0; mt < 2; ++mt)
                #pragma unroll
                for (int r = 0; r < 4; ++r) {
                    float p = __builtin_amdgcn_exp2f(sacc[mt][nt][r] - mnew[mt][r]);
                    rsum[mt][r] += p;
                    plds[(w * 32 + mt * 16 + quad * 4 + r) * 136 + nt * 16 + l16] = (bf16)p;
                }
        #pragma unroll
        for (int d = 1; d < 16; d <<= 1)
            #pragma unroll
            for (int mt = 0; mt < 2; ++mt)
                #pragma unroll
                for (int r = 0; r < 4; ++r)
                    rsum[mt][r] += __shfl_xor(rsum[mt][r], d);
        #pragma unroll
        for (int mt = 0; mt < 2; ++mt)
            #pragma unroll
            for (int r = 0; r < 4; ++r) {
                lrow[mt][r] = lrow[mt][r] * alpha[mt][r] + rsum[mt][r];
                mrow[mt][r] = mnew[mt][r];
            }
        #pragma unroll
        for (int mt = 0; mt < 2; ++mt)
            #pragma unroll
            for (int dt = 0; dt < 4; ++dt)
                #pragma unroll
                for (int r = 0; r < 4; ++r)
                    oacc[mt][dt][r] *= alpha[mt][r];

        __syncthreads();   // safety: P LDS writes -> A-fragment reads (wave-private regions)

        // ---- O += P V  (P as A-operand from LDS, Vt as NT B-operand) ----
        #pragma unroll
        for (int ks = 0; ks < 4; ++ks) {
            bf16x8 paf0 = *(const bf16x8*)&plds[(w * 32 + l16) * 136 + ks * 32 + quad * 8];
            bf16x8 paf1 = *(const bf16x8*)&plds[(w * 32 + 16 + l16) * 136 + ks * 32 + quad * 8];
            #pragma unroll
            for (int dt = 0; dt < 4; ++dt) {
                int vrow = (b * NHEAD + h) * HDIM + dt * 16 + l16;
                bf16x8 vf = *(const bf16x8*)(vtg + (size_t)vrow * S_LEN + k0 + ks * 32 + quad * 8);
                oacc[0][dt] = MFMA_BF16(paf0, vf, oacc[0][dt]);
                oacc[1][dt] = MFMA_BF16(paf1, vf, oacc[1][dt]);
            }
        }
    }

    // ---- epilogue: ctx[b,s,h,d] bf16 ----
    #pragma unroll
    for (int mt = 0; mt < 2; ++mt)
        #pragma unroll
        for (int r = 0; r < 4; ++r) {
            float inv = lrow[mt][r] > 0.f ? 1.f / lrow[mt][r] : 0.f;
            size_t row = (size_t)(b * S_LEN + q0 + w * 32 + mt * 16 + quad * 4 + r);
            #pragma unroll
            for (int dt = 0; dt < 4; ++dt)
                ctx[row * EMB + h * HDIM + dt * 16 + l16] = (bf16)(oacc[mt][dt][r] * inv);
        }
}

extern "C" void kernel_launch(void* const* d_in, const int* in_sizes, int n_in,
                              void* d_out, int out_size, void* d_ws, size_t ws_size,
                              hipStream_t stream)
{
    const float* x   = (const float*)d_in[0];
    const int*  mask = (const int*)d_in[1];
    const float* Wq  = (const float*)d_in[2];
    const float* bq  = (const float*)d_in[3];
    const float* Wk  = (const float*)d_in[4];
    const float* bk  = (const float*)d_in[5];
    const float* Wv  = (const float*)d_in[6];
    const float* bv  = (const float*)d_in[7];
    const float* Wo  = (const float*)d_in[8];
    const float* bo  = (const float*)d_in[9];

    const size_t mat_elems = (size_t)NTOK * EMB;   // 8.4M bf16 = 16 MB each
    bf16* qb = (bf16*)d_ws;
    bf16* kb = qb + mat_elems;
    bf16* vt = kb + mat_elems;     // V stored transposed [b,h,d,s]
    bf16* cx = vt + mat_elems;     // attention output [b,s,h,d]
    (void)ws_size; (void)in_sizes; (void)n_in; (void)out_size;

    dim3 gg(NTOK / 128, EMB / 128);   // 64 x 8
    gemm_nt_kern<true, 0><<<gg, 256, 0, stream>>>(x, Wq, bq, qb);
    gemm_nt_kern<true, 0><<<gg, 256, 0, stream>>>(x, Wk, bk, kb);
    gemm_nt_kern<true, 1><<<gg, 256, 0, stream>>>(x, Wv, bv, vt);
    flash_attn_kern<<<dim3(S_LEN / 128, NHEAD, BATCH), 256, 0, stream>>>(qb, kb, vt, mask, cx);
    gemm_nt_kern<false, 2><<<gg, 256, 0, stream>>>(cx, Wo, bo, (float*)d_out);
}

// Round 2
// 429.540 us; speedup vs baseline: 1.6942x; 1.6942x over previous
//
#include <hip/hip_runtime.h>

typedef __bf16 bf16;
typedef __attribute__((ext_vector_type(4))) bf16 bf16x4;
typedef __attribute__((ext_vector_type(8))) bf16 bf16x8;
typedef __attribute__((ext_vector_type(4))) float f32x4;
typedef __attribute__((ext_vector_type(4))) int i32x4;

#define MFMA_BF16(a, b, c) __builtin_amdgcn_mfma_f32_16x16x32_bf16((a), (b), (c), 0, 0, 0)

constexpr int S_LEN = 2048;
constexpr int EMB   = 1024;
constexpr int NHEAD = 16;
constexpr int HDIM  = 64;
constexpr int BATCH = 4;
constexpr int NTOK  = BATCH * S_LEN;   // 8192

// async global->LDS, 16B per lane (m97 pattern: LDS dest must be uniform base + lane*16)
__device__ __forceinline__ void gload_lds16(const bf16* g, bf16* l) {
    __builtin_amdgcn_global_load_lds(
        (const __attribute__((address_space(1))) void*)g,
        (__attribute__((address_space(3))) void*)l, 16, 0, 0);
}

// ---------------------------------------------------------------------------
// fp32 -> bf16 elementwise convert (n4 = n/4)
// ---------------------------------------------------------------------------
__global__ __launch_bounds__(256)
void cvt_f32_bf16(const float* __restrict__ src, bf16* __restrict__ dst, int n4) {
    int i = blockIdx.x * 256 + threadIdx.x;
    if (i < n4) {
        f32x4 v = ((const f32x4*)src)[i];
        bf16x4 o;
        o[0] = (bf16)v[0]; o[1] = (bf16)v[1]; o[2] = (bf16)v[2]; o[3] = (bf16)v[3];
        ((bf16x4*)dst)[i] = o;
    }
}

// ---------------------------------------------------------------------------
// NT GEMM, m97 structure: C[M,N] = A[M,K]*W[N,K]^T + bias. 128x128 tile, BK=32,
// 256 thr = 4 waves 2x2 (64x64 each). global_load_lds(16B) staging, unpadded
// 64B LDS rows. fused=1: grid (64,24), seg = y>>3 picks {Q,K,V}; V scatters to
// Vt[b,h,d,s] with packed 8B stores. fused=0: grid (64,8), fp32 output.
// ---------------------------------------------------------------------------
__global__ __launch_bounds__(256)
void gemm_bt(const bf16* __restrict__ A,
             const bf16* __restrict__ W0, const bf16* __restrict__ W1, const bf16* __restrict__ W2,
             const float* __restrict__ b0, const float* __restrict__ b1, const float* __restrict__ b2,
             void* __restrict__ d0, void* __restrict__ d1, void* __restrict__ d2,
             int fused)
{
    __shared__ bf16 al[128 * 32];
    __shared__ bf16 bl[128 * 32];

    int seg, mode, n0;
    if (fused) { seg = blockIdx.y >> 3; n0 = (blockIdx.y & 7) * 128; mode = (seg == 2) ? 1 : 0; }
    else       { seg = 0;              n0 = blockIdx.y * 128;        mode = 2; }
    const bf16*  W    = seg == 0 ? W0 : (seg == 1 ? W1 : W2);
    const float* bias = seg == 0 ? b0 : (seg == 1 ? b1 : b2);
    void*        C    = seg == 0 ? d0 : (seg == 1 ? d1 : d2);

    const int tid  = threadIdx.x;
    const int lane = tid & 63;
    const int w    = tid >> 6;
    const int quad = lane >> 4;
    const int l16  = lane & 15;
    const int wm   = (w >> 1) * 64;
    const int wn   = (w & 1) * 64;
    const int m0   = blockIdx.x * 128;

    f32x4 acc[4][4] = {};

    for (int k0 = 0; k0 < EMB; k0 += 32) {
        #pragma unroll
        for (int c = 0; c < 2; ++c) {
            int idx = c * 256 + tid;            // LDS addr = idx*16B: uniform base + lane*16 per wave
            int row = idx >> 2, kc = idx & 3;
            gload_lds16(A + (size_t)(m0 + row) * EMB + k0 + kc * 8, &al[idx * 8]);
            gload_lds16(W + (size_t)(n0 + row) * EMB + k0 + kc * 8, &bl[idx * 8]);
        }
        __syncthreads();

        bf16x8 afrag[4], bfrag[4];
        #pragma unroll
        for (int t = 0; t < 4; ++t)
            afrag[t] = *(const bf16x8*)&al[(wm + t * 16 + l16) * 32 + quad * 8];
        #pragma unroll
        for (int t = 0; t < 4; ++t)
            bfrag[t] = *(const bf16x8*)&bl[(wn + t * 16 + l16) * 32 + quad * 8];

        #pragma unroll
        for (int mt = 0; mt < 4; ++mt)
            #pragma unroll
            for (int nt = 0; nt < 4; ++nt)
                acc[mt][nt] = MFMA_BF16(afrag[mt], bfrag[nt], acc[mt][nt]);

        __syncthreads();
    }

    // epilogue: C-layout row = quad*4+r, col = l16 (m89-verified)
    #pragma unroll
    for (int mt = 0; mt < 4; ++mt) {
        #pragma unroll
        for (int nt = 0; nt < 4; ++nt) {
            int col = n0 + wn + nt * 16 + l16;
            float bv = bias[col];
            int row0 = m0 + wm + mt * 16 + quad * 4;
            if (mode == 1) {
                int bb = row0 >> 11, s0 = row0 & 2047;
                int hh = col >> 6,   d  = col & 63;
                bf16x4 pk;
                #pragma unroll
                for (int r = 0; r < 4; ++r) pk[r] = (bf16)(acc[mt][nt][r] + bv);
                *(bf16x4*)((bf16*)C + (size_t)((bb * NHEAD + hh) * HDIM + d) * S_LEN + s0) = pk;
            } else if (mode == 0) {
                #pragma unroll
                for (int r = 0; r < 4; ++r)
                    ((bf16*)C)[(size_t)(row0 + r) * EMB + col] = (bf16)(acc[mt][nt][r] + bv);
            } else {
                #pragma unroll
                for (int r = 0; r < 4; ++r)
                    ((float*)C)[(size_t)(row0 + r) * EMB + col] = acc[mt][nt][r] + bv;
            }
        }
    }
}

// ---------------------------------------------------------------------------
// Flash attention, S^T orientation: sacc = mfma(kf, qf) so C-layout puts
// query on l16 (lane) and keys on (nt, quad*4+r) regs. P pack -> ds_write_b64,
// softmax reductions = in-register + 2 shuffles, no in-loop __syncthreads
// (all LDS regions wave-private; wave64 is lockstep).
// Grid (S/128, H, B), 256 thr = 4 waves; wave owns 32 query rows.
// ---------------------------------------------------------------------------
__global__ __launch_bounds__(256)
void flash_attn(const bf16* __restrict__ qg, const bf16* __restrict__ kg,
                const bf16* __restrict__ vtg, const int* __restrict__ maskg,
                bf16* __restrict__ ctx)
{
    __shared__ bf16  plds[128 * 136];     // 272B rows (16B-aligned)
    __shared__ float bias_lds[2048];      // additive mask bias per key
    __shared__ float stat_lds[4][32];     // per-wave alpha / inv-l broadcast

    const int tid  = threadIdx.x;
    const int lane = tid & 63;
    const int w    = tid >> 6;
    const int quad = lane >> 4;
    const int l16  = lane & 15;
    const int b    = blockIdx.z;
    const int h    = blockIdx.y;
    const int q0   = blockIdx.x * 128;
    const float scale = 0.125f * 1.44269504088896340736f;  // 1/sqrt(64) * log2(e)

    // mask -> f32 additive bias in LDS (each thread covers 8 keys)
    {
        int i = tid * 8;
        i32x4 m0v = *(const i32x4*)(maskg + b * S_LEN + i);
        i32x4 m1v = *(const i32x4*)(maskg + b * S_LEN + i + 4);
        f32x4 f0, f1;
        #pragma unroll
        for (int r = 0; r < 4; ++r) {
            f0[r] = m0v[r] ? 0.f : -3.0e38f;
            f1[r] = m1v[r] ? 0.f : -3.0e38f;
        }
        *(f32x4*)&bias_lds[i]     = f0;
        *(f32x4*)&bias_lds[i + 4] = f1;
    }
    __syncthreads();

    // Q fragments (B-operand: n=query=l16, k=quad*8+j), resident all kernel
    bf16x8 qf[2][2];
    #pragma unroll
    for (int mt = 0; mt < 2; ++mt)
        #pragma unroll
        for (int ks = 0; ks < 2; ++ks) {
            int row = b * S_LEN + q0 + w * 32 + mt * 16 + l16;
            qf[mt][ks] = *(const bf16x8*)(qg + (size_t)row * EMB + h * HDIM + ks * 32 + quad * 8);
        }

    float mrow[2] = {-1e30f, -1e30f}, lrow[2] = {0.f, 0.f};
    f32x4 oacc[2][4] = {};

    for (int kt = 0; kt < 16; ++kt) {
        const int k0 = kt * 128;

        // ---- S^T = K Q^T: C[key=quad*4+r][query=l16] per (nt,mt) tile ----
        f32x4 sacc[8][2] = {};
        #pragma unroll
        for (int nt = 0; nt < 8; ++nt) {
            int krow = b * S_LEN + k0 + nt * 16 + l16;
            #pragma unroll
            for (int ks = 0; ks < 2; ++ks) {
                bf16x8 kf = *(const bf16x8*)(kg + (size_t)krow * EMB + h * HDIM + ks * 32 + quad * 8);
                sacc[nt][0] = MFMA_BF16(kf, qf[0][ks], sacc[nt][0]);
                sacc[nt][1] = MFMA_BF16(kf, qf[1][ks], sacc[nt][1]);
            }
        }

        // ---- scale + mask bias + max over keys (in-reg + 2 shuffles) ----
        float rmax[2] = {-3.0e38f, -3.0e38f};
        #pragma unroll
        for (int nt = 0; nt < 8; ++nt) {
            f32x4 b4 = *(const f32x4*)&bias_lds[k0 + nt * 16 + quad * 4];
            #pragma unroll
            for (int mt = 0; mt < 2; ++mt)
                #pragma unroll
                for (int r = 0; r < 4; ++r) {
                    float sv = sacc[nt][mt][r] * scale + b4[r];
                    sacc[nt][mt][r] = sv;
                    rmax[mt] = fmaxf(rmax[mt], sv);
                }
        }
        #pragma unroll
        for (int mt = 0; mt < 2; ++mt) {
            rmax[mt] = fmaxf(rmax[mt], __shfl_xor(rmax[mt], 16));
            rmax[mt] = fmaxf(rmax[mt], __shfl_xor(rmax[mt], 32));
        }

        // ---- online softmax: exp2, packed P writes (b64), sum ----
        float mnew[2], alpha[2], rsum[2] = {0.f, 0.f};
        #pragma unroll
        for (int mt = 0; mt < 2; ++mt) {
            mnew[mt]  = fmaxf(mrow[mt], rmax[mt]);
            alpha[mt] = __builtin_amdgcn_exp2f(mrow[mt] - mnew[mt]);
            mrow[mt]  = mnew[mt];
        }
        #pragma unroll
        for (int nt = 0; nt < 8; ++nt)
            #pragma unroll
            for (int mt = 0; mt < 2; ++mt) {
                bf16x4 pk;
                #pragma unroll
                for (int r = 0; r < 4; ++r) {
                    float p = __builtin_amdgcn_exp2f(sacc[nt][mt][r] - mnew[mt]);
                    rsum[mt] += p;
                    pk[r] = (bf16)p;
                }
                *(bf16x4*)&plds[(w * 32 + mt * 16 + l16) * 136 + nt * 16 + quad * 4] = pk;
            }
        #pragma unroll
        for (int mt = 0; mt < 2; ++mt) {
            rsum[mt] += __shfl_xor(rsum[mt], 16);
            rsum[mt] += __shfl_xor(rsum[mt], 32);
            lrow[mt] = lrow[mt] * alpha[mt] + rsum[mt];
        }

        // ---- broadcast alpha to C-layout rows via LDS (wave-private) ----
        if (quad == 0) { stat_lds[w][l16] = alpha[0]; stat_lds[w][16 + l16] = alpha[1]; }
        #pragma unroll
        for (int mt2 = 0; mt2 < 2; ++mt2) {
            f32x4 a4 = *(const f32x4*)&stat_lds[w][mt2 * 16 + quad * 4];
            #pragma unroll
            for (int dt = 0; dt < 4; ++dt)
                #pragma unroll
                for (int r = 0; r < 4; ++r)
                    oacc[mt2][dt][r] *= a4[r];
        }

        // ---- O += P V  (P A-operand from LDS b128, Vt NT B-operand) ----
        #pragma unroll
        for (int ks = 0; ks < 4; ++ks) {
            bf16x8 pf0 = *(const bf16x8*)&plds[(w * 32 + l16) * 136 + ks * 32 + quad * 8];
            bf16x8 pf1 = *(const bf16x8*)&plds[(w * 32 + 16 + l16) * 136 + ks * 32 + quad * 8];
            #pragma unroll
            for (int dt = 0; dt < 4; ++dt) {
                bf16x8 vf = *(const bf16x8*)(vtg + (size_t)((b * NHEAD + h) * HDIM + dt * 16 + l16) * S_LEN
                                             + k0 + ks * 32 + quad * 8);
                oacc[0][dt] = MFMA_BF16(pf0, vf, oacc[0][dt]);
                oacc[1][dt] = MFMA_BF16(pf1, vf, oacc[1][dt]);
            }
        }
    }

    // ---- epilogue: 1/l broadcast, store ctx[b,s,h,d] ----
    if (quad == 0) {
        stat_lds[w][l16]      = lrow[0] > 0.f ? 1.f / lrow[0] : 0.f;
        stat_lds[w][16 + l16] = lrow[1] > 0.f ? 1.f / lrow[1] : 0.f;
    }
    #pragma unroll
    for (int mt2 = 0; mt2 < 2; ++mt2) {
        f32x4 inv4 = *(const f32x4*)&stat_lds[w][mt2 * 16 + quad * 4];
        #pragma unroll
        for (int r = 0; r < 4; ++r) {
            size_t row = (size_t)(b * S_LEN + q0 + w * 32 + mt2 * 16 + quad * 4 + r);
            #pragma unroll
            for (int dt = 0; dt < 4; ++dt)
                ctx[row * EMB + h * HDIM + dt * 16 + l16] = (bf16)(oacc[mt2][dt][r] * inv4[r]);
        }
    }
}

extern "C" void kernel_launch(void* const* d_in, const int* in_sizes, int n_in,
                              void* d_out, int out_size, void* d_ws, size_t ws_size,
                              hipStream_t stream)
{
    const float* x   = (const float*)d_in[0];
    const int*  mask = (const int*)d_in[1];
    const float* Wq  = (const float*)d_in[2];
    const float* bq  = (const float*)d_in[3];
    const float* Wk  = (const float*)d_in[4];
    const float* bk  = (const float*)d_in[5];
    const float* Wv  = (const float*)d_in[6];
    const float* bv  = (const float*)d_in[7];
    const float* Wo  = (const float*)d_in[8];
    const float* bo  = (const float*)d_in[9];
    (void)in_sizes; (void)n_in; (void)out_size; (void)ws_size;

    const size_t me = (size_t)NTOK * EMB;    // 8.4M
    const size_t we = (size_t)EMB * EMB;     // 1M
    bf16* xb  = (bf16*)d_ws;
    bf16* qb  = xb  + me;
    bf16* kb  = qb  + me;
    bf16* vt  = kb  + me;     // V transposed [b,h,d,s]
    bf16* wqb = vt  + me;
    bf16* wkb = wqb + we;
    bf16* wvb = wkb + we;
    bf16* wob = wvb + we;
    bf16* cx  = xb;           // alias: xb consumed by qkv gemm before flash writes cx

    cvt_f32_bf16<<<(int)(me / 4 / 256), 256, 0, stream>>>(x,  xb,  (int)(me / 4));
    cvt_f32_bf16<<<(int)(we / 4 / 256), 256, 0, stream>>>(Wq, wqb, (int)(we / 4));
    cvt_f32_bf16<<<(int)(we / 4 / 256), 256, 0, stream>>>(Wk, wkb, (int)(we / 4));
    cvt_f32_bf16<<<(int)(we / 4 / 256), 256, 0, stream>>>(Wv, wvb, (int)(we / 4));
    cvt_f32_bf16<<<(int)(we / 4 / 256), 256, 0, stream>>>(Wo, wob, (int)(we / 4));

    gemm_bt<<<dim3(NTOK / 128, 24), 256, 0, stream>>>(
        xb, wqb, wkb, wvb, bq, bk, bv, qb, kb, vt, 1);

    flash_attn<<<dim3(S_LEN / 128, NHEAD, BATCH), 256, 0, stream>>>(qb, kb, vt, mask, cx);

    gemm_bt<<<dim3(NTOK / 128, EMB / 128), 256, 0, stream>>>(
        cx, wob, wob, wob, bo, bo, bo, d_out, d_out, d_out, 0);
}